// Round 6
// baseline (333.543 us; speedup 1.0000x reference)
//
#include <hip/hip_runtime.h>

typedef unsigned short ushort_t;
typedef __attribute__((ext_vector_type(8))) short short8;   // 8 x bf16 (MFMA A/B frag)
typedef __attribute__((ext_vector_type(4))) float floatx4;  // MFMA C/D frag

// Problem constants (fixed by the reference)
// N=4000 nodes, E=60000 edges, M=16, C=64, H=64, HEADS=8, A=8, VC=8, CE=32, Z=90
// Composite-weight block layout (floats), per role stride RS:
//   WsWa [64*64] @0, WtWa [64*64] @4096, WeWa [32*64] @8192,
//   PsW [64*8] @10240, PtW [64*8] @10752, WeWvWo [32*8] @11264
constexpr int RS = 11520;

__device__ inline float bf2f(ushort_t u) {
    union { unsigned int i; float f; } v; v.i = ((unsigned int)u) << 16; return v.f;
}
__device__ inline ushort_t f2bf(float f) {
    union { float f; unsigned int i; } v; v.f = f;
    unsigned int b = v.i + 0x7FFFu + ((v.i >> 16) & 1u);  // RNE
    return (ushort_t)(b >> 16);
}

// ---------------------------------------------------------------------------
// Kernel A: weight composites.  grid = (6 tasks, 2 roles), 256 thr
// ---------------------------------------------------------------------------
__global__ __launch_bounds__(256) void k_composites(
    const float* __restrict__ Ws0, const float* __restrict__ Wt0, const float* __restrict__ We0,
    const float* __restrict__ Wa0, const float* __restrict__ Wv0, const float* __restrict__ Wo0,
    const float* __restrict__ Ws1, const float* __restrict__ Wt1, const float* __restrict__ We1,
    const float* __restrict__ Wa1, const float* __restrict__ Wv1, const float* __restrict__ Wo1,
    float* __restrict__ cmp)
{
    int task = blockIdx.x;   // 0..5
    int r    = blockIdx.y;   // 0..1
    const float* Ws = r ? Ws1 : Ws0;
    const float* Wt = r ? Wt1 : Wt0;
    const float* We = r ? We1 : We0;
    const float* Wa = r ? Wa1 : Wa0;
    const float* Wv = r ? Wv1 : Wv0;
    const float* Wo = r ? Wo1 : Wo0;
    float* base = cmp + r * RS;

    if (task == 0 || task == 1) {
        const float* L = task ? Wt : Ws;
        float* out = base + task * 4096;
        for (int idx = threadIdx.x; idx < 4096; idx += 256) {
            int c = idx >> 6, j = idx & 63;
            float a = 0.f;
            for (int k = 0; k < 64; ++k) a += L[c * 64 + k] * Wa[k * 64 + j];
            out[idx] = a;
        }
    } else if (task == 2) {
        float* out = base + 8192;
        for (int idx = threadIdx.x; idx < 2048; idx += 256) {
            int ce = idx >> 6, j = idx & 63;
            float a = 0.f;
            for (int k = 0; k < 64; ++k) a += We[ce * 64 + k] * Wa[k * 64 + j];
            out[idx] = a;
        }
    } else {
        // WvWo fold: WvWo[k,h] = sum_vc Wv[k, h*8+vc] * Wo[h*8+vc]
        const float* L = (task == 3) ? Ws : (task == 4) ? Wt : We;
        int rows = (task == 5) ? 32 : 64;
        float* out = base + ((task == 3) ? 10240 : (task == 4) ? 10752 : 11264);
        for (int idx = threadIdx.x; idx < rows * 8; idx += 256) {
            int c = idx >> 3, h = idx & 7;
            float a = 0.f;
            for (int k = 0; k < 64; ++k) {
                float wv = 0.f;
                #pragma unroll
                for (int aa = 0; aa < 8; ++aa) wv += Wv[k * 64 + h * 8 + aa] * Wo[h * 8 + aa];
                a += L[c * 64 + k] * wv;
            }
            out[idx] = a;
        }
    }
}

// ---------------------------------------------------------------------------
// Kernel B: per-node precompute via MFMA, one wave per node (grid-stride).
// Layouts (HW-verified): A[m=lane&15][k=(lane>>4)*8+j],
// B[k=(lane>>4)*8+j][n=lane&15], C/D: col=lane&15, row=(lane>>4)*4+reg.
// ---------------------------------------------------------------------------
__device__ inline short8 bfragW(const float* __restrict__ W, int colBase, int kBase,
                                int q, int n) {
    short8 f;
    #pragma unroll
    for (int j = 0; j < 8; ++j)
        f[j] = (short)f2bf(W[(kBase + q * 8 + j) * 64 + colBase + n]);
    return f;
}
__device__ inline short8 bfragP(const float* __restrict__ P0, const float* __restrict__ P1,
                                int kBase, int q, int n) {
    const float* P = (n < 8) ? P0 : P1;
    int c = n & 7;
    short8 f;
    #pragma unroll
    for (int j = 0; j < 8; ++j)
        f[j] = (short)f2bf(P[(kBase + q * 8 + j) * 8 + c]);
    return f;
}

#define MFMA(a, b, c) __builtin_amdgcn_mfma_f32_16x16x32_bf16((a), (b), (c), 0, 0, 0)

__global__ __launch_bounds__(256, 2) void k_node(
    const float* __restrict__ x, const int* __restrict__ mask,
    const float* __restrict__ cmp,
    float* __restrict__ psrc, float* __restrict__ ptgt,
    ushort_t* __restrict__ srcA, ushort_t* __restrict__ tgtA,
    int N, int totWaves)
{
    int wid  = (int)((blockIdx.x * blockDim.x + threadIdx.x) >> 6);
    int lane = threadIdx.x & 63;
    int q    = lane >> 4;     // quad 0..3
    int n16  = lane & 15;     // 0..15

    short8 Bs0[4][2], Bs1[4][2], Bt0[4][2], Bt1[4][2];
    #pragma unroll
    for (int t = 0; t < 4; ++t) {
        #pragma unroll
        for (int kh = 0; kh < 2; ++kh) {
            Bs0[t][kh] = bfragW(cmp,             t * 16, kh * 32, q, n16);
            Bs1[t][kh] = bfragW(cmp + RS,        t * 16, kh * 32, q, n16);
            Bt0[t][kh] = bfragW(cmp + 4096,      t * 16, kh * 32, q, n16);
            Bt1[t][kh] = bfragW(cmp + RS + 4096, t * 16, kh * 32, q, n16);
        }
    }
    short8 Bp[2], Bq[2];
    #pragma unroll
    for (int kh = 0; kh < 2; ++kh) {
        Bp[kh] = bfragP(cmp + 10240, cmp + RS + 10240, kh * 32, q, n16);
        Bq[kh] = bfragP(cmp + 10752, cmp + RS + 10752, kh * 32, q, n16);
    }

    const floatx4 zero = {0.f, 0.f, 0.f, 0.f};

    for (int nd = wid; nd < N; nd += totWaves) {
        const float* xp = x + (size_t)nd * 1024 + n16 * 64 + q * 8;
        float4 v0 = *(const float4*)(xp);
        float4 v1 = *(const float4*)(xp + 4);
        float4 v2 = *(const float4*)(xp + 32);
        float4 v3 = *(const float4*)(xp + 36);
        short8 a0, a1;
        a0[0] = (short)f2bf(v0.x); a0[1] = (short)f2bf(v0.y);
        a0[2] = (short)f2bf(v0.z); a0[3] = (short)f2bf(v0.w);
        a0[4] = (short)f2bf(v1.x); a0[5] = (short)f2bf(v1.y);
        a0[6] = (short)f2bf(v1.z); a0[7] = (short)f2bf(v1.w);
        a1[0] = (short)f2bf(v2.x); a1[1] = (short)f2bf(v2.y);
        a1[2] = (short)f2bf(v2.z); a1[3] = (short)f2bf(v2.w);
        a1[4] = (short)f2bf(v3.x); a1[5] = (short)f2bf(v3.y);
        a1[6] = (short)f2bf(v3.z); a1[7] = (short)f2bf(v3.w);

        int rsel = (mask[nd] != 0);

        {
            floatx4 c0 = zero, c1 = zero, c2 = zero, c3 = zero;
            c0 = MFMA(a0, Bs0[0][0], c0); c0 = MFMA(a1, Bs0[0][1], c0);
            c1 = MFMA(a0, Bs0[1][0], c1); c1 = MFMA(a1, Bs0[1][1], c1);
            c2 = MFMA(a0, Bs0[2][0], c2); c2 = MFMA(a1, Bs0[2][1], c2);
            c3 = MFMA(a0, Bs0[3][0], c3); c3 = MFMA(a1, Bs0[3][1], c3);
            ushort_t* sp = srcA + (size_t)nd * 2048 + (q * 4) * 64 + n16;
            #pragma unroll
            for (int rr = 0; rr < 4; ++rr) {
                sp[rr * 64 +  0] = f2bf(c0[rr]);
                sp[rr * 64 + 16] = f2bf(c1[rr]);
                sp[rr * 64 + 32] = f2bf(c2[rr]);
                sp[rr * 64 + 48] = f2bf(c3[rr]);
            }
        }
        {
            floatx4 c0 = zero, c1 = zero, c2 = zero, c3 = zero;
            c0 = MFMA(a0, Bs1[0][0], c0); c0 = MFMA(a1, Bs1[0][1], c0);
            c1 = MFMA(a0, Bs1[1][0], c1); c1 = MFMA(a1, Bs1[1][1], c1);
            c2 = MFMA(a0, Bs1[2][0], c2); c2 = MFMA(a1, Bs1[2][1], c2);
            c3 = MFMA(a0, Bs1[3][0], c3); c3 = MFMA(a1, Bs1[3][1], c3);
            ushort_t* sp = srcA + (size_t)nd * 2048 + 1024 + (q * 4) * 64 + n16;
            #pragma unroll
            for (int rr = 0; rr < 4; ++rr) {
                sp[rr * 64 +  0] = f2bf(c0[rr]);
                sp[rr * 64 + 16] = f2bf(c1[rr]);
                sp[rr * 64 + 32] = f2bf(c2[rr]);
                sp[rr * 64 + 48] = f2bf(c3[rr]);
            }
        }
        {
            floatx4 c0 = zero, c1 = zero, c2 = zero, c3 = zero;
            if (rsel) {
                c0 = MFMA(a0, Bt1[0][0], c0); c0 = MFMA(a1, Bt1[0][1], c0);
                c1 = MFMA(a0, Bt1[1][0], c1); c1 = MFMA(a1, Bt1[1][1], c1);
                c2 = MFMA(a0, Bt1[2][0], c2); c2 = MFMA(a1, Bt1[2][1], c2);
                c3 = MFMA(a0, Bt1[3][0], c3); c3 = MFMA(a1, Bt1[3][1], c3);
            } else {
                c0 = MFMA(a0, Bt0[0][0], c0); c0 = MFMA(a1, Bt0[0][1], c0);
                c1 = MFMA(a0, Bt0[1][0], c1); c1 = MFMA(a1, Bt0[1][1], c1);
                c2 = MFMA(a0, Bt0[2][0], c2); c2 = MFMA(a1, Bt0[2][1], c2);
                c3 = MFMA(a0, Bt0[3][0], c3); c3 = MFMA(a1, Bt0[3][1], c3);
            }
            ushort_t* tp = tgtA + (size_t)nd * 1024 + (q * 4) * 64 + n16;
            #pragma unroll
            for (int rr = 0; rr < 4; ++rr) {
                tp[rr * 64 +  0] = f2bf(c0[rr]);
                tp[rr * 64 + 16] = f2bf(c1[rr]);
                tp[rr * 64 + 32] = f2bf(c2[rr]);
                tp[rr * 64 + 48] = f2bf(c3[rr]);
            }
        }
        {
            floatx4 cp = zero;
            cp = MFMA(a0, Bp[0], cp); cp = MFMA(a1, Bp[1], cp);
            if (q == 0) {
                int r = n16 >> 3, h = n16 & 7;
                float* pp = psrc + (size_t)nd * 48 + r * 24 + h;
                pp[0]  = cp[1];
                pp[8]  = cp[2];
                pp[16] = cp[3];
            }
            floatx4 cq = zero;
            cq = MFMA(a0, Bq[0], cq); cq = MFMA(a1, Bq[1], cq);
            if (q == 0 && (n16 >> 3) == rsel) {
                int h = n16 & 7;
                float* pp = ptgt + (size_t)nd * 24 + h;
                pp[0]  = cq[1];
                pp[8]  = cq[2];
                pp[16] = cq[3];
            }
        }
    }
}

// ---------------------------------------------------------------------------
// CSR build (dst only): histogram -> single-block scan -> fill
// ---------------------------------------------------------------------------
__global__ __launch_bounds__(256) void k_hist(
    const int* __restrict__ ei, int* __restrict__ cnt_d, int E)
{
    int e = blockIdx.x * 256 + threadIdx.x;
    if (e < E) atomicAdd(&cnt_d[ei[E + e]], 1);
}

__global__ __launch_bounds__(256) void k_scan(
    const int* __restrict__ cnt_d,
    int* __restrict__ base_d, int* __restrict__ woff_d, int N)
{
    __shared__ int part[256];
    int tid = threadIdx.x;
    int chunk = (N + 255) / 256;
    int lo = tid * chunk, hi = min(lo + chunk, N);
    int sum = 0;
    for (int i = lo; i < hi; ++i) sum += cnt_d[i];
    part[tid] = sum;
    __syncthreads();
    for (int off = 1; off < 256; off <<= 1) {
        int v = (tid >= off) ? part[tid - off] : 0;
        __syncthreads();
        part[tid] += v;
        __syncthreads();
    }
    int run = tid ? part[tid - 1] : 0;
    for (int i = lo; i < hi; ++i) { base_d[i] = run; woff_d[i] = run; run += cnt_d[i]; }
}

__global__ __launch_bounds__(256) void k_fill(
    const int* __restrict__ ei, int* __restrict__ woff_d,
    int* __restrict__ cd_e, int* __restrict__ cd_src, int E)
{
    int e = blockIdx.x * 256 + threadIdx.x;
    if (e < E) {
        int s = ei[e], t = ei[E + e];
        int q = atomicAdd(&woff_d[t], 1);
        cd_e[q] = e; cd_src[q] = s;
    }
}

// ---------------------------------------------------------------------------
// Kernel C: FUSED attention. One block (4 waves) per dst node; waves process
// the node's in-edges in parallel. Softmax denominators distribute:
//   out[c] = sum_h [ sum_e ex*(ps+pt) + w0[1+c]*ex*ej ][c,h] / den[h]
// so numerators P/W and den accumulate in ONE pass; LDS-reduce across waves.
// No f0s/exb/ejb/den buffers, no atomics.
// ---------------------------------------------------------------------------
__global__ __launch_bounds__(256) void k_attn(
    const int* __restrict__ cd_e, const int* __restrict__ cd_src,
    const float* __restrict__ dist, const int* __restrict__ zn,
    const int* __restrict__ mask,
    const float* __restrict__ wig, const float* __restrict__ cmp,
    const float* __restrict__ embs0, const float* __restrict__ embt0, const float* __restrict__ wd0,
    const float* __restrict__ embs1, const float* __restrict__ embt1, const float* __restrict__ wd1,
    const float* __restrict__ va0, const float* __restrict__ va1,
    const ushort_t* __restrict__ srcA, const ushort_t* __restrict__ tgtA,
    const float* __restrict__ psrc, const float* __restrict__ ptgt,
    const int* __restrict__ base_d, const int* __restrict__ cnt_d,
    float* __restrict__ out, int N)
{
    int nd = blockIdx.x;
    int num = cnt_d[nd];
    if (num == 0) {
        if (threadIdx.x < 3) out[nd * 3 + threadIdx.x] = 0.f;
        return;
    }
    int wv = threadIdx.x >> 6;   // wave 0..3
    int j  = threadIdx.x & 63;
    int beg = base_d[nd];
    int r = (mask[nd] != 0);     // block-uniform

    const float* embs = r ? embs1 : embs0;
    const float* embt = r ? embt1 : embt0;
    const float* wd   = r ? wd1   : wd0;
    float vav = r ? va1[j] : va0[j];
    const float* WeWa   = cmp + r * RS + 8192;
    const float* WeWvWo = cmp + r * RS + 11264;

    int ce = j & 31, h8 = j & 7;
    int zt = zn[nd];
    float wdv = wd[ce];
    float embtv = embt[zt * 32 + ce];

    // target fragment (shared by all the node's edges) in registers
    float y[16];
    const ushort_t* tp = tgtA + (size_t)nd * 1024 + j;
    #pragma unroll
    for (int n = 0; n < 16; ++n) y[n] = bf2f(tp[n * 64]);

    int c = j >> 3;              // output row for lanes t<24
    bool act = (j < 24);
    float ptv = act ? ptgt[(size_t)nd * 24 + j] : 0.f;

    float den_acc = 0.f;         // valid on lanes j<8 (head j)
    float accP = 0.f, accW = 0.f;  // valid on lanes j<24 (c=j>>3, h=j&7)

    for (int i = wv; i < num; i += 4) {
        int p = beg + i;
        int e = cd_e[p], src = cd_src[p];
        float d = dist[e];

        float z = d * wdv + embs[zn[src] * 32 + ce] + embtv;
        float es = z / (1.f + __expf(-z));   // silu

        float f0a = 0.f, ej = 0.f;
        #pragma unroll
        for (int cc = 0; cc < 32; ++cc) {
            float ev = __shfl(es, cc, 64);
            f0a += ev * WeWa[cc * 64 + j];
            ej  += ev * WeWvWo[cc * 8 + h8];
        }

        const ushort_t* sp = srcA + (size_t)src * 2048 + r * 1024 + j;
        const float* w0 = wig + (size_t)e * 256;
        #pragma unroll
        for (int n = 0; n < 16; ++n) f0a += w0[n] * (bf2f(sp[n * 64]) + y[n]);

        float la = f0a > 0.f ? f0a : 0.2f * f0a;   // leaky_relu(0.2)
        float val = la * vav;
        val += __shfl_xor(val, 1);
        val += __shfl_xor(val, 2);
        val += __shfl_xor(val, 4);                  // logit per 8-lane head group
        float ex = __expf(val);                     // lane j holds head (j>>3)'s value
        float exh = __shfl(ex, (j & 7) * 8);        // lane j gets head (j&7)'s ex
        if (j < 8) den_acc += exh;
        if (act) {
            float psv = psrc[(size_t)src * 48 + r * 24 + j];
            accP += exh * (psv + ptv);
            accW += w0[1 + c] * exh * ej;           // ej on lane j is head (j&7)'s ✓
        }
    }

    // cross-wave reduction
    __shared__ float sden[4][8];
    __shared__ float sP[4][24];
    __shared__ float sW[4][24];
    if (j < 8) sden[wv][j] = den_acc;
    if (act) { sP[wv][j] = accP; sW[wv][j] = accW; }
    __syncthreads();
    if (wv == 0 && act) {
        int hh = j & 7;
        float P = sP[0][j] + sP[1][j] + sP[2][j] + sP[3][j];
        float W = sW[0][j] + sW[1][j] + sW[2][j] + sW[3][j];
        float dn = sden[0][hh] + sden[1][hh] + sden[2][hh] + sden[3][hh];
        float v = (P + W) / (dn + 1e-9f);
        v += __shfl_xor(v, 1);
        v += __shfl_xor(v, 2);
        v += __shfl_xor(v, 4);                      // sum over heads within row c
        if (hh == 0) out[nd * 3 + c] = v;
    }
}

// ---------------------------------------------------------------------------
extern "C" void kernel_launch(void* const* d_in, const int* in_sizes, int n_in,
                              void* d_out, int out_size, void* d_ws, size_t ws_size,
                              hipStream_t stream) {
    const float* x    = (const float*)d_in[0];
    const int*   zn   = (const int*)d_in[1];
    const float* dist = (const float*)d_in[2];
    const int*   ei   = (const int*)d_in[3];
    const int*   mask = (const int*)d_in[4];
    const float* wig  = (const float*)d_in[5];
    // per role: emb_s, emb_t, w_d, We, Ws, Wt, Wa, va, Wv, Wo
    const float* fs[10]; const float* dn[10];
    for (int i = 0; i < 10; ++i) { fs[i] = (const float*)d_in[6 + i]; dn[i] = (const float*)d_in[16 + i]; }

    int N = in_sizes[1];   // atomic_numbers count
    int E = in_sizes[2];   // edge_distance count

    // workspace carve-up
    float* cmp  = (float*)d_ws;                    // 2*RS
    float* psrc = cmp + 2 * RS;                    // N*48
    float* ptgt = psrc + (size_t)N * 48;           // N*24
    int* cnt_d  = (int*)(ptgt + (size_t)N * 24);   // N
    int* base_d = cnt_d + N;                       // N
    int* woff_d = base_d + N;                      // N
    int* cd_e   = woff_d + N;                      // E
    int* cd_src = cd_e + E;                        // E
    size_t off = (size_t)((char*)(cd_src + E) - (char*)d_ws);
    off = (off + 15) & ~(size_t)15;
    ushort_t* srcA = (ushort_t*)((char*)d_ws + off);      // N*2048 bf16
    ushort_t* tgtA = srcA + (size_t)N * 2048;             // N*1024 bf16
    // total ~26 MB

    hipMemsetAsync(cnt_d, 0, (size_t)N * sizeof(int), stream);

    k_composites<<<dim3(6, 2), 256, 0, stream>>>(
        fs[4], fs[5], fs[3], fs[6], fs[8], fs[9],
        dn[4], dn[5], dn[3], dn[6], dn[8], dn[9], cmp);

    int nodeBlocks = 512;
    int totWaves = nodeBlocks * (256 / 64);
    k_node<<<nodeBlocks, 256, 0, stream>>>(x, mask, cmp, psrc, ptgt, srcA, tgtA, N, totWaves);

    k_hist<<<(E + 255) / 256, 256, 0, stream>>>(ei, cnt_d, E);
    k_scan<<<1, 256, 0, stream>>>(cnt_d, base_d, woff_d, N);
    k_fill<<<(E + 255) / 256, 256, 0, stream>>>(ei, woff_d, cd_e, cd_src, E);

    k_attn<<<N, 256, 0, stream>>>(
        cd_e, cd_src, dist, zn, mask, wig, cmp,
        fs[0], fs[1], fs[2], dn[0], dn[1], dn[2],
        fs[7], dn[7], srcA, tgtA, psrc, ptgt, base_d, cnt_d,
        (float*)d_out, N);
}

// Round 7
// 283.965 us; speedup vs baseline: 1.1746x; 1.1746x over previous
//
#include <hip/hip_runtime.h>

typedef unsigned short ushort_t;
typedef __attribute__((ext_vector_type(8))) short short8;   // 8 x bf16 (MFMA A/B frag)
typedef __attribute__((ext_vector_type(4))) float floatx4;  // MFMA C/D frag

// Problem constants (fixed by the reference)
// N=4000 nodes, E=60000 edges, M=16, C=64, H=64, HEADS=8, A=8, VC=8, CE=32, Z=90
// Composite-weight block layout (floats), per role stride RS:
//   WsWa [64*64] @0, WtWa [64*64] @4096, WeWa [32*64] @8192,
//   PsW [64*8] @10240, PtW [64*8] @10752, WeWvWo [32*8] @11264
constexpr int RS = 11520;

__device__ inline float bf2f(ushort_t u) {
    union { unsigned int i; float f; } v; v.i = ((unsigned int)u) << 16; return v.f;
}
__device__ inline ushort_t f2bf(float f) {
    union { float f; unsigned int i; } v; v.f = f;
    unsigned int b = v.i + 0x7FFFu + ((v.i >> 16) & 1u);  // RNE
    return (ushort_t)(b >> 16);
}

// ---------------------------------------------------------------------------
// Kernel A: weight composites + workspace zero-init (folded memsets).
// grid = (7 tasks, 2 roles), 256 thr
// ---------------------------------------------------------------------------
__global__ __launch_bounds__(256) void k_composites(
    const float* __restrict__ Ws0, const float* __restrict__ Wt0, const float* __restrict__ We0,
    const float* __restrict__ Wa0, const float* __restrict__ Wv0, const float* __restrict__ Wo0,
    const float* __restrict__ Ws1, const float* __restrict__ Wt1, const float* __restrict__ We1,
    const float* __restrict__ Wa1, const float* __restrict__ Wv1, const float* __restrict__ Wo1,
    float* __restrict__ cmp, float* __restrict__ den, int* __restrict__ cnt_s,
    float* __restrict__ out, int N)
{
    int task = blockIdx.x;   // 0..6
    int r    = blockIdx.y;   // 0..1
    if (task == 6) {         // zero-init duty
        if (r == 0) {
            for (int i = threadIdx.x; i < N * 8; i += 256) den[i] = 0.f;
            for (int i = threadIdx.x; i < N; i += 256) cnt_s[i] = 0;
        } else {
            for (int i = threadIdx.x; i < N * 3; i += 256) out[i] = 0.f;
        }
        return;
    }
    const float* Ws = r ? Ws1 : Ws0;
    const float* Wt = r ? Wt1 : Wt0;
    const float* We = r ? We1 : We0;
    const float* Wa = r ? Wa1 : Wa0;
    const float* Wv = r ? Wv1 : Wv0;
    const float* Wo = r ? Wo1 : Wo0;
    float* base = cmp + r * RS;

    if (task == 0 || task == 1) {
        const float* L = task ? Wt : Ws;
        float* outp = base + task * 4096;
        for (int idx = threadIdx.x; idx < 4096; idx += 256) {
            int c = idx >> 6, j = idx & 63;
            float a = 0.f;
            for (int k = 0; k < 64; ++k) a += L[c * 64 + k] * Wa[k * 64 + j];
            outp[idx] = a;
        }
    } else if (task == 2) {
        float* outp = base + 8192;
        for (int idx = threadIdx.x; idx < 2048; idx += 256) {
            int ce = idx >> 6, j = idx & 63;
            float a = 0.f;
            for (int k = 0; k < 64; ++k) a += We[ce * 64 + k] * Wa[k * 64 + j];
            outp[idx] = a;
        }
    } else {
        // WvWo fold: WvWo[k,h] = sum_vc Wv[k, h*8+vc] * Wo[h*8+vc]
        const float* L = (task == 3) ? Ws : (task == 4) ? Wt : We;
        int rows = (task == 5) ? 32 : 64;
        float* outp = base + ((task == 3) ? 10240 : (task == 4) ? 10752 : 11264);
        for (int idx = threadIdx.x; idx < rows * 8; idx += 256) {
            int c = idx >> 3, h = idx & 7;
            float a = 0.f;
            for (int k = 0; k < 64; ++k) {
                float wv = 0.f;
                #pragma unroll
                for (int aa = 0; aa < 8; ++aa) wv += Wv[k * 64 + h * 8 + aa] * Wo[h * 8 + aa];
                a += L[c * 64 + k] * wv;
            }
            outp[idx] = a;
        }
    }
}

// ---------------------------------------------------------------------------
// Kernel B: per-node precompute via MFMA, one wave per node (grid-stride).
// Layouts (HW-verified): A[m=lane&15][k=(lane>>4)*8+j],
// B[k=(lane>>4)*8+j][n=lane&15], C/D: col=lane&15, row=(lane>>4)*4+reg.
// ---------------------------------------------------------------------------
__device__ inline short8 bfragW(const float* __restrict__ W, int colBase, int kBase,
                                int q, int n) {
    short8 f;
    #pragma unroll
    for (int j = 0; j < 8; ++j)
        f[j] = (short)f2bf(W[(kBase + q * 8 + j) * 64 + colBase + n]);
    return f;
}
__device__ inline short8 bfragP(const float* __restrict__ P0, const float* __restrict__ P1,
                                int kBase, int q, int n) {
    const float* P = (n < 8) ? P0 : P1;
    int c = n & 7;
    short8 f;
    #pragma unroll
    for (int j = 0; j < 8; ++j)
        f[j] = (short)f2bf(P[(kBase + q * 8 + j) * 8 + c]);
    return f;
}

#define MFMA(a, b, c) __builtin_amdgcn_mfma_f32_16x16x32_bf16((a), (b), (c), 0, 0, 0)

__global__ __launch_bounds__(256, 2) void k_node(
    const float* __restrict__ x, const int* __restrict__ mask,
    const float* __restrict__ cmp,
    float* __restrict__ psrc, float* __restrict__ ptgt,
    ushort_t* __restrict__ srcA, ushort_t* __restrict__ tgtA,
    int N, int totWaves)
{
    int wid  = (int)((blockIdx.x * blockDim.x + threadIdx.x) >> 6);
    int lane = threadIdx.x & 63;
    int q    = lane >> 4;     // quad 0..3
    int n16  = lane & 15;     // 0..15

    short8 Bs0[4][2], Bs1[4][2], Bt0[4][2], Bt1[4][2];
    #pragma unroll
    for (int t = 0; t < 4; ++t) {
        #pragma unroll
        for (int kh = 0; kh < 2; ++kh) {
            Bs0[t][kh] = bfragW(cmp,             t * 16, kh * 32, q, n16);
            Bs1[t][kh] = bfragW(cmp + RS,        t * 16, kh * 32, q, n16);
            Bt0[t][kh] = bfragW(cmp + 4096,      t * 16, kh * 32, q, n16);
            Bt1[t][kh] = bfragW(cmp + RS + 4096, t * 16, kh * 32, q, n16);
        }
    }
    short8 Bp[2], Bq[2];
    #pragma unroll
    for (int kh = 0; kh < 2; ++kh) {
        Bp[kh] = bfragP(cmp + 10240, cmp + RS + 10240, kh * 32, q, n16);
        Bq[kh] = bfragP(cmp + 10752, cmp + RS + 10752, kh * 32, q, n16);
    }

    const floatx4 zero = {0.f, 0.f, 0.f, 0.f};

    for (int nd = wid; nd < N; nd += totWaves) {
        const float* xp = x + (size_t)nd * 1024 + n16 * 64 + q * 8;
        float4 v0 = *(const float4*)(xp);
        float4 v1 = *(const float4*)(xp + 4);
        float4 v2 = *(const float4*)(xp + 32);
        float4 v3 = *(const float4*)(xp + 36);
        short8 a0, a1;
        a0[0] = (short)f2bf(v0.x); a0[1] = (short)f2bf(v0.y);
        a0[2] = (short)f2bf(v0.z); a0[3] = (short)f2bf(v0.w);
        a0[4] = (short)f2bf(v1.x); a0[5] = (short)f2bf(v1.y);
        a0[6] = (short)f2bf(v1.z); a0[7] = (short)f2bf(v1.w);
        a1[0] = (short)f2bf(v2.x); a1[1] = (short)f2bf(v2.y);
        a1[2] = (short)f2bf(v2.z); a1[3] = (short)f2bf(v2.w);
        a1[4] = (short)f2bf(v3.x); a1[5] = (short)f2bf(v3.y);
        a1[6] = (short)f2bf(v3.z); a1[7] = (short)f2bf(v3.w);

        int rsel = (mask[nd] != 0);

        {
            floatx4 c0 = zero, c1 = zero, c2 = zero, c3 = zero;
            c0 = MFMA(a0, Bs0[0][0], c0); c0 = MFMA(a1, Bs0[0][1], c0);
            c1 = MFMA(a0, Bs0[1][0], c1); c1 = MFMA(a1, Bs0[1][1], c1);
            c2 = MFMA(a0, Bs0[2][0], c2); c2 = MFMA(a1, Bs0[2][1], c2);
            c3 = MFMA(a0, Bs0[3][0], c3); c3 = MFMA(a1, Bs0[3][1], c3);
            ushort_t* sp = srcA + (size_t)nd * 2048 + (q * 4) * 64 + n16;
            #pragma unroll
            for (int rr = 0; rr < 4; ++rr) {
                sp[rr * 64 +  0] = f2bf(c0[rr]);
                sp[rr * 64 + 16] = f2bf(c1[rr]);
                sp[rr * 64 + 32] = f2bf(c2[rr]);
                sp[rr * 64 + 48] = f2bf(c3[rr]);
            }
        }
        {
            floatx4 c0 = zero, c1 = zero, c2 = zero, c3 = zero;
            c0 = MFMA(a0, Bs1[0][0], c0); c0 = MFMA(a1, Bs1[0][1], c0);
            c1 = MFMA(a0, Bs1[1][0], c1); c1 = MFMA(a1, Bs1[1][1], c1);
            c2 = MFMA(a0, Bs1[2][0], c2); c2 = MFMA(a1, Bs1[2][1], c2);
            c3 = MFMA(a0, Bs1[3][0], c3); c3 = MFMA(a1, Bs1[3][1], c3);
            ushort_t* sp = srcA + (size_t)nd * 2048 + 1024 + (q * 4) * 64 + n16;
            #pragma unroll
            for (int rr = 0; rr < 4; ++rr) {
                sp[rr * 64 +  0] = f2bf(c0[rr]);
                sp[rr * 64 + 16] = f2bf(c1[rr]);
                sp[rr * 64 + 32] = f2bf(c2[rr]);
                sp[rr * 64 + 48] = f2bf(c3[rr]);
            }
        }
        {
            floatx4 c0 = zero, c1 = zero, c2 = zero, c3 = zero;
            if (rsel) {
                c0 = MFMA(a0, Bt1[0][0], c0); c0 = MFMA(a1, Bt1[0][1], c0);
                c1 = MFMA(a0, Bt1[1][0], c1); c1 = MFMA(a1, Bt1[1][1], c1);
                c2 = MFMA(a0, Bt1[2][0], c2); c2 = MFMA(a1, Bt1[2][1], c2);
                c3 = MFMA(a0, Bt1[3][0], c3); c3 = MFMA(a1, Bt1[3][1], c3);
            } else {
                c0 = MFMA(a0, Bt0[0][0], c0); c0 = MFMA(a1, Bt0[0][1], c0);
                c1 = MFMA(a0, Bt0[1][0], c1); c1 = MFMA(a1, Bt0[1][1], c1);
                c2 = MFMA(a0, Bt0[2][0], c2); c2 = MFMA(a1, Bt0[2][1], c2);
                c3 = MFMA(a0, Bt0[3][0], c3); c3 = MFMA(a1, Bt0[3][1], c3);
            }
            ushort_t* tp = tgtA + (size_t)nd * 1024 + (q * 4) * 64 + n16;
            #pragma unroll
            for (int rr = 0; rr < 4; ++rr) {
                tp[rr * 64 +  0] = f2bf(c0[rr]);
                tp[rr * 64 + 16] = f2bf(c1[rr]);
                tp[rr * 64 + 32] = f2bf(c2[rr]);
                tp[rr * 64 + 48] = f2bf(c3[rr]);
            }
        }
        {
            floatx4 cp = zero;
            cp = MFMA(a0, Bp[0], cp); cp = MFMA(a1, Bp[1], cp);
            if (q == 0) {
                int r = n16 >> 3, h = n16 & 7;
                float* pp = psrc + (size_t)nd * 48 + r * 24 + h;
                pp[0]  = cp[1];
                pp[8]  = cp[2];
                pp[16] = cp[3];
            }
            floatx4 cq = zero;
            cq = MFMA(a0, Bq[0], cq); cq = MFMA(a1, Bq[1], cq);
            if (q == 0 && (n16 >> 3) == rsel) {
                int h = n16 & 7;
                float* pp = ptgt + (size_t)nd * 24 + h;
                pp[0]  = cq[1];
                pp[8]  = cq[2];
                pp[16] = cq[3];
            }
        }
    }
}

// ---------------------------------------------------------------------------
// CSR build (src side only): histogram -> single-block scan -> fill
// ---------------------------------------------------------------------------
__global__ __launch_bounds__(256) void k_hist(
    const int* __restrict__ ei, int* __restrict__ cnt_s, int E)
{
    int e = blockIdx.x * 256 + threadIdx.x;
    if (e < E) atomicAdd(&cnt_s[ei[e]], 1);
}

__global__ __launch_bounds__(256) void k_scan(
    const int* __restrict__ cnt_s, int* __restrict__ woff_s, int N)
{
    __shared__ int part[256];
    int tid = threadIdx.x;
    int chunk = (N + 255) / 256;
    int lo = tid * chunk, hi = min(lo + chunk, N);
    int sum = 0;
    for (int i = lo; i < hi; ++i) sum += cnt_s[i];
    part[tid] = sum;
    __syncthreads();
    for (int off = 1; off < 256; off <<= 1) {
        int v = (tid >= off) ? part[tid - off] : 0;
        __syncthreads();
        part[tid] += v;
        __syncthreads();
    }
    int run = tid ? part[tid - 1] : 0;
    for (int i = lo; i < hi; ++i) { woff_s[i] = run; run += cnt_s[i]; }
}

__global__ __launch_bounds__(256) void k_fill(
    const int* __restrict__ ei, int* __restrict__ woff_s,
    int* __restrict__ cs_e, int* __restrict__ cs_src, int* __restrict__ cs_dst, int E)
{
    int e = blockIdx.x * 256 + threadIdx.x;
    if (e < E) {
        int s = ei[e], t = ei[E + e];
        int p = atomicAdd(&woff_s[s], 1);
        cs_e[p] = e; cs_src[p] = s; cs_dst[p] = t;
    }
}

// ---------------------------------------------------------------------------
// Kernel C: per-edge logits (R2 body), iterated in SRC-SORTED order with an
// XCD-aware block swizzle: chunk = (b%8)*(B/8) + b/8, so each XCD's blocks
// cover a contiguous src range (~2 MB srcA slice -> resident in its 4 MiB
// L2 instead of replicated across all 8 XCDs).  One wave per edge.
// ---------------------------------------------------------------------------
__global__ __launch_bounds__(256) void k_logits(
    const int* __restrict__ cs_e, const int* __restrict__ cs_src,
    const int* __restrict__ cs_dst,
    const float* __restrict__ dist, const int* __restrict__ zn,
    const int* __restrict__ mask,
    const float* __restrict__ wig, const float* __restrict__ cmp,
    const float* __restrict__ embs0, const float* __restrict__ embt0, const float* __restrict__ wd0,
    const float* __restrict__ embs1, const float* __restrict__ embt1, const float* __restrict__ wd1,
    const float* __restrict__ va0, const float* __restrict__ va1,
    const ushort_t* __restrict__ srcA, const ushort_t* __restrict__ tgtA,
    float* __restrict__ den, float* __restrict__ exb, float* __restrict__ ejb,
    int E, int B8)
{
    int wv = threadIdx.x >> 6, j = threadIdx.x & 63;
    int b = blockIdx.x;
    int chunk = (b & 7) * B8 + (b >> 3);   // XCD-contiguous src ranges
    int p = chunk * 4 + wv;
    if (p >= E) return;
    int e = cs_e[p], src = cs_src[p], dst = cs_dst[p];
    int r = (mask[dst] != 0);
    float d = dist[e];
    int zs = zn[src], zt = zn[dst];

    // edge scalar embedding (32 values, computed in lanes via j&31)
    float es;
    {
        int ce = j & 31;
        float z = r ? (d * wd1[ce] + embs1[zs * 32 + ce] + embt1[zt * 32 + ce])
                    : (d * wd0[ce] + embs0[zs * 32 + ce] + embt0[zt * 32 + ce]);
        es = z / (1.f + __expf(-z));   // silu
    }

    const float* WeWa   = cmp + r * RS + 8192;
    const float* WeWvWo = cmp + r * RS + 11264;
    int h8 = j & 7;
    float f0a = 0.f, ej = 0.f;
    #pragma unroll
    for (int ce = 0; ce < 32; ++ce) {
        float ev = __shfl(es, ce, 64);
        f0a += ev * WeWa[ce * 64 + j];
        ej  += ev * WeWvWo[ce * 8 + h8];
    }

    // f0a[j] += sum_n D[0,n] * (srcA_r[src][n,j] + tgtA[dst][n,j])
    const ushort_t* sp = srcA + (size_t)src * 2048 + r * 1024 + j;
    const ushort_t* tp = tgtA + (size_t)dst * 1024 + j;
    const float* w0 = wig + (size_t)e * 256;
    #pragma unroll
    for (int n = 0; n < 16; ++n) {
        float sv = bf2f(sp[n * 64]) + bf2f(tp[n * 64]);
        f0a += w0[n] * sv;
    }

    float la = f0a > 0.f ? f0a : 0.2f * f0a;           // leaky_relu(0.2)
    float val = la * (r ? va1[j] : va0[j]);
    val += __shfl_xor(val, 1);
    val += __shfl_xor(val, 2);
    val += __shfl_xor(val, 4);                          // logit per 8-lane group
    float ex = __expf(val);                             // no-max softmax (logits bounded)
    if (h8 == 0) {
        atomicAdd(&den[dst * 8 + (j >> 3)], ex);
        exb[(size_t)e * 8 + (j >> 3)] = ex;
    }
    if (j < 8) ejb[(size_t)e * 8 + j] = ej;
}

// ---------------------------------------------------------------------------
// Kernel D: per-edge value + scatter (R2 verbatim).  8 lanes per edge.
// ---------------------------------------------------------------------------
__global__ __launch_bounds__(256) void k_scatter(
    const int* __restrict__ ei, const int* __restrict__ mask,
    const float* __restrict__ wig,
    const float* __restrict__ psrc, const float* __restrict__ ptgt,
    const float* __restrict__ exb, const float* __restrict__ ejb,
    const float* __restrict__ den, float* __restrict__ out, int E)
{
    int t = threadIdx.x;
    int g = t >> 3, h = t & 7;
    int e = blockIdx.x * 32 + g;
    if (e >= E) return;
    int src = ei[e], dst = ei[E + e];
    int r = (mask[dst] != 0);
    float alpha = exb[(size_t)e * 8 + h] / (den[dst * 8 + h] + 1e-9f);
    const float* ps = psrc + (size_t)src * 48 + r * 24;
    const float* pt = ptgt + (size_t)dst * 24;
    float s0 = alpha * (ps[h]      + pt[h]);
    float s1 = alpha * (ps[8 + h]  + pt[8 + h]);
    float s2 = alpha * (ps[16 + h] + pt[16 + h]);
    float se = alpha * ejb[(size_t)e * 8 + h];
    #pragma unroll
    for (int off = 1; off < 8; off <<= 1) {
        s0 += __shfl_xor(s0, off);
        s1 += __shfl_xor(s1, off);
        s2 += __shfl_xor(s2, off);
        se += __shfl_xor(se, off);
    }
    if (h == 0) {
        const float* w0 = wig + (size_t)e * 256;   // D[0, :]
        atomicAdd(&out[dst * 3 + 0], s0 + w0[1] * se);
        atomicAdd(&out[dst * 3 + 1], s1 + w0[2] * se);
        atomicAdd(&out[dst * 3 + 2], s2 + w0[3] * se);
    }
}

// ---------------------------------------------------------------------------
extern "C" void kernel_launch(void* const* d_in, const int* in_sizes, int n_in,
                              void* d_out, int out_size, void* d_ws, size_t ws_size,
                              hipStream_t stream) {
    const float* x    = (const float*)d_in[0];
    const int*   zn   = (const int*)d_in[1];
    const float* dist = (const float*)d_in[2];
    const int*   ei   = (const int*)d_in[3];
    const int*   mask = (const int*)d_in[4];
    const float* wig  = (const float*)d_in[5];
    // per role: emb_s, emb_t, w_d, We, Ws, Wt, Wa, va, Wv, Wo
    const float* fs[10]; const float* dn[10];
    for (int i = 0; i < 10; ++i) { fs[i] = (const float*)d_in[6 + i]; dn[i] = (const float*)d_in[16 + i]; }

    int N = in_sizes[1];   // atomic_numbers count
    int E = in_sizes[2];   // edge_distance count

    // workspace carve-up
    float* cmp  = (float*)d_ws;                    // 2*RS
    float* den  = cmp + 2 * RS;                    // N*8
    float* exb  = den + (size_t)N * 8;             // E*8
    float* ejb  = exb + (size_t)E * 8;             // E*8
    float* psrc = ejb + (size_t)E * 8;             // N*48
    float* ptgt = psrc + (size_t)N * 48;           // N*24
    int* cnt_s  = (int*)(ptgt + (size_t)N * 24);   // N
    int* woff_s = cnt_s + N;                       // N
    int* cs_e   = woff_s + N;                      // E
    int* cs_src = cs_e + E;                        // E
    int* cs_dst = cs_src + E;                      // E
    size_t off = (size_t)((char*)(cs_dst + E) - (char*)d_ws);
    off = (off + 15) & ~(size_t)15;
    ushort_t* srcA = (ushort_t*)((char*)d_ws + off);      // N*2048 bf16
    ushort_t* tgtA = srcA + (size_t)N * 2048;             // N*1024 bf16
    // total ~31 MB

    k_composites<<<dim3(7, 2), 256, 0, stream>>>(
        fs[4], fs[5], fs[3], fs[6], fs[8], fs[9],
        dn[4], dn[5], dn[3], dn[6], dn[8], dn[9],
        cmp, den, cnt_s, (float*)d_out, N);

    int nodeBlocks = 512;
    int totWaves = nodeBlocks * (256 / 64);
    k_node<<<nodeBlocks, 256, 0, stream>>>(x, mask, cmp, psrc, ptgt, srcA, tgtA, N, totWaves);

    k_hist<<<(E + 255) / 256, 256, 0, stream>>>(ei, cnt_s, E);
    k_scan<<<1, 256, 0, stream>>>(cnt_s, woff_s, N);
    k_fill<<<(E + 255) / 256, 256, 0, stream>>>(ei, woff_s, cs_e, cs_src, cs_dst, E);

    int nchunks = (E + 3) / 4;            // 4 edges (waves) per block
    int B8 = (nchunks + 7) / 8;
    int B = B8 * 8;
    k_logits<<<B, 256, 0, stream>>>(
        cs_e, cs_src, cs_dst, dist, zn, mask, wig, cmp,
        fs[0], fs[1], fs[2], dn[0], dn[1], dn[2],
        fs[7], dn[7], srcA, tgtA, den, exb, ejb, E, B8);

    k_scatter<<<(E + 31) / 32, 256, 0, stream>>>(
        ei, mask, wig, psrc, ptgt, exb, ejb, den, (float*)d_out, E);
}